// Round 2
// baseline (443.646 us; speedup 1.0000x reference)
//
#include <hip/hip_runtime.h>
#include <math.h>

// Problem constants (from reference): N=100000, E=1600000, D_IN=D_H=128, D_OUT=47
#define DH 128
#define DOUT 47
#define BN_EPS 1e-5f

typedef __attribute__((ext_vector_type(8))) short short8;
typedef __attribute__((ext_vector_type(4))) float float4v;
typedef __attribute__((ext_vector_type(2))) float float2v;

// ---------------------------------------------------------------------------
// bf16 pack/unpack (RNE).
// ---------------------------------------------------------------------------
__device__ __forceinline__ unsigned bf16_rne(float f) {
    unsigned u = __float_as_uint(f);
    return (u + 0x7fffu + ((u >> 16) & 1u)) >> 16;
}
__device__ __forceinline__ unsigned pack_bf2(float a, float b) {
    return (bf16_rne(a) & 0xffffu) | (bf16_rne(b) << 16);
}
__device__ __forceinline__ float2 unpack_bf2(unsigned u) {
    return make_float2(__uint_as_float(u << 16),
                       __uint_as_float(u & 0xffff0000u));
}

// packed accumulate: a.(lo,hi) += (bf16lo(u), bf16hi(u)) via v_pk_add_f32.
// Same value/order as two scalar adds -> bitwise-identical results.
__device__ __forceinline__ void bf2_acc(float2v& a, unsigned u) {
    float2v f;
    f.x = __uint_as_float(u << 16);
    f.y = __uint_as_float(u & 0xffff0000u);
    asm("v_pk_add_f32 %0, %0, %1" : "+v"(a) : "v"(f));
}

// ---------------------------------------------------------------------------
// Pre-scaled-table GCN: table row g[s] = dinv[s] * (X@W)[s]; edge record is a
// bare 4-B src index; pads/tail point at zeroed sentinel row N.
// ---------------------------------------------------------------------------

// prep: block 0 -> W1 transpose+bf16 (+ zero sentinel row of bufA),
//       block 1 -> W2, blocks >=2 -> zero counts.
__global__ __launch_bounds__(256) void prep_k(const float* __restrict__ W1,
                                              const float* __restrict__ W2,
                                              unsigned* __restrict__ W1b,
                                              unsigned* __restrict__ W2b,
                                              int* __restrict__ counts,
                                              unsigned* __restrict__ bufA, int n) {
    int tid = threadIdx.x;
    if (blockIdx.x >= 2) {
        int i = (blockIdx.x - 2) * 256 + tid;
        if (i < n) counts[i] = 0;
        return;
    }
    const float* W = blockIdx.x ? W2 : W1;
    unsigned* Wb = blockIdx.x ? W2b : W1b;
    if (blockIdx.x == 0 && tid < 64) bufA[(size_t)n * 64 + tid] = 0;  // sentinel row
    for (int p = tid; p < 128 * 32; p += 256) {
        int nn = p >> 5;
        int k0 = (p & 31) << 2;
        float f0 = W[(size_t)(k0 + 0) * 128 + nn];
        float f1 = W[(size_t)(k0 + 1) * 128 + nn];
        float f2 = W[(size_t)(k0 + 2) * 128 + nn];
        float f3 = W[(size_t)(k0 + 3) * 128 + nn];
        uint2 v;
        v.x = pack_bf2(f0, f1);
        v.y = pack_bf2(f2, f3);
        *(uint2*)(Wb + (size_t)nn * 64 + (k0 >> 1)) = v;
    }
}

__global__ __launch_bounds__(256) void count_rank_k(const int* __restrict__ dst,
                                                    int* __restrict__ counts,
                                                    int* __restrict__ rank, int e) {
    int i0 = (blockIdx.x * 256 + threadIdx.x) * 4;
    if (i0 + 4 <= e) {
        int4 d4 = *(const int4*)(dst + i0);
        int4 r4;
        r4.x = atomicAdd(&counts[d4.x], 1);
        r4.y = atomicAdd(&counts[d4.y], 1);
        r4.z = atomicAdd(&counts[d4.z], 1);
        r4.w = atomicAdd(&counts[d4.w], 1);
        *(int4*)(rank + i0) = r4;
    } else {
        for (int i = i0; i < e; i++) rank[i] = atomicAdd(&counts[dst[i]], 1);
    }
}

// scan1 scans PADDED counts ((c+7)&~7).
__global__ __launch_bounds__(256) void scan1_k(const int* __restrict__ counts,
                                               int* __restrict__ offsets,
                                               int* __restrict__ blocksums, int n) {
    __shared__ int sd[256];
    int tid = threadIdx.x;
    int base = blockIdx.x * 1024 + tid * 4;
    int v0 = (base + 0 < n) ? ((counts[base + 0] + 7) & ~7) : 0;
    int v1 = (base + 1 < n) ? ((counts[base + 1] + 7) & ~7) : 0;
    int v2 = (base + 2 < n) ? ((counts[base + 2] + 7) & ~7) : 0;
    int v3 = (base + 3 < n) ? ((counts[base + 3] + 7) & ~7) : 0;
    int tsum = v0 + v1 + v2 + v3;
    sd[tid] = tsum;
    __syncthreads();
    for (int off = 1; off < 256; off <<= 1) {
        int x = (tid >= off) ? sd[tid - off] : 0;
        __syncthreads();
        sd[tid] += x;
        __syncthreads();
    }
    if (tid == 255) blocksums[blockIdx.x] = sd[255];
    int run = sd[tid] - tsum;
    if (base + 0 < n) offsets[base + 0] = run;  run += v0;
    if (base + 1 < n) offsets[base + 1] = run;  run += v1;
    if (base + 2 < n) offsets[base + 2] = run;  run += v2;
    if (base + 3 < n) offsets[base + 3] = run;
}

// scan2: exclusive scan of block sums + write el tail sentinels (row n) so
// the agg pipeline's phantom prefetches always read valid row indices.
__global__ __launch_bounds__(128) void scan2_k(int* __restrict__ blocksums, int nb,
                                               int* __restrict__ el, int n) {
    __shared__ int sd[128];
    int tid = threadIdx.x;
    int v = (tid < nb) ? blocksums[tid] : 0;
    sd[tid] = v;
    __syncthreads();
    for (int off = 1; off < 128; off <<= 1) {
        int x = (tid >= off) ? sd[tid - off] : 0;
        __syncthreads();
        sd[tid] += x;
        __syncthreads();
    }
    if (tid < nb) blocksums[tid] = sd[tid] - v;  // exclusive
    int total = sd[127];                         // total padded edges
    if (tid < 96) el[total + tid] = n;           // sentinel tail
}

// finalize: padded offsets, dinv, pad records = sentinel row n.
__global__ void finalize_k(int* __restrict__ offsets,
                           float* __restrict__ dinv, const int* __restrict__ counts,
                           const int* __restrict__ blocksums,
                           int* __restrict__ el, int n) {
    int i = blockIdx.x * 256 + threadIdx.x;
    if (i >= n) return;
    int o = offsets[i] + blocksums[i >> 10];
    offsets[i] = o;
    int c = counts[i];
    dinv[i] = rsqrtf((float)(c + 1));  // +1 self-loop; deg>=1 always
    int cP = (c + 7) & ~7;
    for (int j = o + c; j < o + cP; ++j) el[j] = n;  // pad -> zero row
}

// scatter: atomic-free, 4-B records (src only).
__global__ __launch_bounds__(256) void scatter_k(const int* __restrict__ src,
                                                 const int* __restrict__ dst,
                                                 const int* __restrict__ rank,
                                                 const int* __restrict__ offsets,
                                                 int* __restrict__ el, int e) {
    int i0 = (blockIdx.x * 256 + threadIdx.x) * 4;
    if (i0 + 4 <= e) {
        int4 s4 = *(const int4*)(src + i0);
        int4 d4 = *(const int4*)(dst + i0);
        int4 r4 = *(const int4*)(rank + i0);
        el[offsets[d4.x] + r4.x] = s4.x;
        el[offsets[d4.y] + r4.y] = s4.y;
        el[offsets[d4.z] + r4.z] = s4.z;
        el[offsets[d4.w] + r4.w] = s4.w;
    } else {
        for (int i = i0; i < e; i++) el[offsets[dst[i]] + rank[i]] = src[i];
    }
}

// ---------------------------------------------------------------------------
// MFMA GEMM (layer 1): A fp32 -> bf16 in-register (single mfma per tile;
// x-quantization is the same error class as the accepted bf16 roundings),
// W bf16 [n][k] in LDS. Output row scaled by dinv[row], packed bf16.
// ---------------------------------------------------------------------------
__global__ __launch_bounds__(256) void gemm_mfma_k(const float* __restrict__ A,
                                                   const unsigned* __restrict__ Wb,
                                                   const float* __restrict__ dinv,
                                                   unsigned* __restrict__ Cb, int M) {
    __shared__ ushort Bl[128 * 136];
    int tid = threadIdx.x;
    {
        unsigned* Bu = (unsigned*)Bl;
        for (int q = tid; q < 128 * 16; q += 256) {
            int row = q >> 4;
            int c = (q & 15) << 2;
            uint4 v = *(const uint4*)(Wb + (size_t)row * 64 + c);
            *(uint4*)(Bu + (size_t)row * 68 + c) = v;
        }
    }
    __syncthreads();

    int lane = tid & 63;
    int wv = tid >> 6;
    int quad = lane >> 4;
    int l15 = lane & 15;
    int r0 = blockIdx.x * 64 + wv * 16;
    int mload = r0 + l15;
    if (mload > M - 1) mload = M - 1;
    const float* Ar = A + (size_t)mload * 128 + quad * 8;

    float4v acc[8];
#pragma unroll
    for (int t = 0; t < 8; t++) acc[t] = (float4v){0.f, 0.f, 0.f, 0.f};

    for (int kp = 0; kp < 4; ++kp) {
        float4 a0 = *(const float4*)(Ar + kp * 32);
        float4 a1 = *(const float4*)(Ar + kp * 32 + 4);
        float af[8] = {a0.x, a0.y, a0.z, a0.w, a1.x, a1.y, a1.z, a1.w};
        short8 av;
#pragma unroll
        for (int j = 0; j < 8; j++) av[j] = (short)bf16_rne(af[j]);
        int kb = kp * 32 + quad * 8;
#pragma unroll
        for (int nt = 0; nt < 8; nt++) {
            short8 b8 = *(const short8*)(&Bl[(size_t)(nt * 16 + l15) * 136 + kb]);
            acc[nt] = __builtin_amdgcn_mfma_f32_16x16x32_bf16(av, b8, acc[nt], 0, 0, 0);
        }
    }

    ushort* Cu = (ushort*)Cb;
#pragma unroll
    for (int r = 0; r < 4; r++) {
        int row = r0 + quad * 4 + r;
        if (row < M) {
            float dv = dinv[row];
#pragma unroll
            for (int nt = 0; nt < 8; nt++) {
                Cu[(size_t)row * 128 + nt * 16 + l15] =
                    (ushort)bf16_rne(acc[nt][r] * dv);
            }
        }
    }
}

// ---------------------------------------------------------------------------
// MFMA GEMM (layer 2): A already bf16 packed -> single mfma per tile.
// Output row scaled by dinv[row].
// ---------------------------------------------------------------------------
__global__ __launch_bounds__(256) void gemm_bf16_k(const unsigned* __restrict__ Ab,
                                                   const unsigned* __restrict__ Wb,
                                                   const float* __restrict__ dinv,
                                                   unsigned* __restrict__ Cb, int M) {
    __shared__ ushort Bl[128 * 136];
    int tid = threadIdx.x;
    {
        unsigned* Bu = (unsigned*)Bl;
        for (int q = tid; q < 128 * 16; q += 256) {
            int row = q >> 4;
            int c = (q & 15) << 2;
            uint4 v = *(const uint4*)(Wb + (size_t)row * 64 + c);
            *(uint4*)(Bu + (size_t)row * 68 + c) = v;
        }
    }
    __syncthreads();

    int lane = tid & 63;
    int wv = tid >> 6;
    int quad = lane >> 4;
    int l15 = lane & 15;
    int r0 = blockIdx.x * 64 + wv * 16;
    int mload = r0 + l15;
    if (mload > M - 1) mload = M - 1;
    const unsigned* Ar = Ab + (size_t)mload * 64 + quad * 4;

    float4v acc[8];
#pragma unroll
    for (int t = 0; t < 8; t++) acc[t] = (float4v){0.f, 0.f, 0.f, 0.f};

    for (int kp = 0; kp < 4; ++kp) {
        uint4 a4 = *(const uint4*)(Ar + kp * 16);
        short8 av;
        av[0] = (short)(a4.x & 0xffff); av[1] = (short)(a4.x >> 16);
        av[2] = (short)(a4.y & 0xffff); av[3] = (short)(a4.y >> 16);
        av[4] = (short)(a4.z & 0xffff); av[5] = (short)(a4.z >> 16);
        av[6] = (short)(a4.w & 0xffff); av[7] = (short)(a4.w >> 16);
        int kb = kp * 32 + quad * 8;
#pragma unroll
        for (int nt = 0; nt < 8; nt++) {
            short8 b8 = *(const short8*)(&Bl[(size_t)(nt * 16 + l15) * 136 + kb]);
            acc[nt] = __builtin_amdgcn_mfma_f32_16x16x32_bf16(av, b8, acc[nt], 0, 0, 0);
        }
    }

    ushort* Cu = (ushort*)Cb;
#pragma unroll
    for (int r = 0; r < 4; r++) {
        int row = r0 + quad * 4 + r;
        if (row < M) {
            float dv = dinv[row];
#pragma unroll
            for (int nt = 0; nt < 8; nt++) {
                Cu[(size_t)row * 128 + nt * 16 + l15] =
                    (ushort)bf16_rne(acc[nt][r] * dv);
            }
        }
    }
}

// ---------------------------------------------------------------------------
// Aggregation core v6: 3-buffer modulo-scheduled pipeline (no register
// rotation movs), packed f32 accumulation, and SENTINEL-CLAMPED prefetch:
// any gather issued for a group >= groups targets the zeroed sentinel row n
// (L1-resident) instead of the next node's random rows. This removes the
// ~33% phantom gather traffic the 2-deep rotating pipeline caused.
// Returns UNSCALED sum incl. self row; caller multiplies by dinv[node].
// ---------------------------------------------------------------------------
__device__ __forceinline__ float4 agg_core(const uint2* __restrict__ Hu2,
                                           const int* __restrict__ el,
                                           int start, int cnt, int node, int n,
                                           int li, int half) {
    float2v a01 = {0.f, 0.f};
    float2v a23 = {0.f, 0.f};
    int groups = ((cnt + 7) & ~7) >> 3;
    if (groups > 0) {
        const int* p = el + start + half * 4;
        const int4 sent4 = make_int4(n, n, n, n);

        uint2 A0, A1, A2, A3, B0, B1, B2, B3, C0, C1, C2, C3;

#define GATHER(d0, d1, d2, d3, r)                  \
        d0 = Hu2[(size_t)(r).x * 32 + li];         \
        d1 = Hu2[(size_t)(r).y * 32 + li];         \
        d2 = Hu2[(size_t)(r).z * 32 + li];         \
        d3 = Hu2[(size_t)(r).w * 32 + li];
#define CONSUME(c0, c1, c2, c3)                    \
        bf2_acc(a01, c0.x); bf2_acc(a23, c0.y);    \
        bf2_acc(a01, c1.x); bf2_acc(a23, c1.y);    \
        bf2_acc(a01, c2.x); bf2_acc(a23, c2.y);    \
        bf2_acc(a01, c3.x); bf2_acc(a23, c3.y);

        int4 r = *(const int4*)p;                       // rows of group 0
        GATHER(A0, A1, A2, A3, r)
        r = (groups > 1) ? *(const int4*)(p + 8) : sent4;
        GATHER(B0, B1, B2, B3, r)
        r = (groups > 2) ? *(const int4*)(p + 16) : sent4;
        GATHER(C0, C1, C2, C3, r)
        r = (3 < groups) ? *(const int4*)(p + 24) : sent4;  // rows of group 3

        int g = 0;
        for (;;) {
            CONSUME(A0, A1, A2, A3)                     // group g
            if (g + 1 >= groups) break;
            GATHER(A0, A1, A2, A3, r)                   // group g+3 (or sentinel)
            r = (g + 4 < groups) ? *(const int4*)(p + 8 * (g + 4)) : sent4;

            CONSUME(B0, B1, B2, B3)                     // group g+1
            if (g + 2 >= groups) break;
            GATHER(B0, B1, B2, B3, r)                   // group g+4 (or sentinel)
            r = (g + 5 < groups) ? *(const int4*)(p + 8 * (g + 5)) : sent4;

            CONSUME(C0, C1, C2, C3)                     // group g+2
            if (g + 3 >= groups) break;
            GATHER(C0, C1, C2, C3, r)                   // group g+5 (or sentinel)
            r = (g + 6 < groups) ? *(const int4*)(p + 8 * (g + 6)) : sent4;
            g += 3;
        }
#undef GATHER
#undef CONSUME
    }
    float4 acc = make_float4(a01.x, a01.y, a23.x, a23.y);
    acc.x += __shfl_xor(acc.x, 32);
    acc.y += __shfl_xor(acc.y, 32);
    acc.z += __shfl_xor(acc.z, 32);
    acc.w += __shfl_xor(acc.w, 32);
    uint2 sv = Hu2[(size_t)node * 32 + li];  // self row (pre-scaled by dinv[node])
    float2 s0 = unpack_bf2(sv.x);
    float2 s1 = unpack_bf2(sv.y);
    acc.x += s0.x; acc.y += s0.y; acc.z += s1.x; acc.w += s1.y;
    return acc;
}

// Layer 1: *dinv, + b1, BN(eval), ReLU -> H1 packed bf16
__global__ __launch_bounds__(256) void agg1_k(
    const unsigned* __restrict__ H, const int* __restrict__ el,
    const int* __restrict__ offsets, const int* __restrict__ counts,
    const float* __restrict__ dinv, const float* __restrict__ b1,
    const float* __restrict__ gamma, const float* __restrict__ beta,
    const float* __restrict__ mean, const float* __restrict__ var,
    unsigned* __restrict__ H1b, int n) {
    int lane = threadIdx.x & 63;
    int li = lane & 31;
    int half = lane >> 5;
    int node = blockIdx.x * 4 + (threadIdx.x >> 6);
    if (node >= n) return;
    float4 acc = agg_core((const uint2*)H, el, offsets[node], counts[node],
                          node, n, li, half);
    if (half == 0) {
        float dv = dinv[node];
        int f0 = li * 4;
        float4 bb = *(const float4*)(b1 + f0);
        float4 mm = *(const float4*)(mean + f0);
        float4 vv = *(const float4*)(var + f0);
        float4 gg = *(const float4*)(gamma + f0);
        float4 be = *(const float4*)(beta + f0);
        float4 o;
        o.x = fmaxf((acc.x * dv + bb.x - mm.x) * rsqrtf(vv.x + BN_EPS) * gg.x + be.x, 0.f);
        o.y = fmaxf((acc.y * dv + bb.y - mm.y) * rsqrtf(vv.y + BN_EPS) * gg.y + be.y, 0.f);
        o.z = fmaxf((acc.z * dv + bb.z - mm.z) * rsqrtf(vv.z + BN_EPS) * gg.z + be.z, 0.f);
        o.w = fmaxf((acc.w * dv + bb.w - mm.w) * rsqrtf(vv.w + BN_EPS) * gg.w + be.w, 0.f);
        uint2 pk;
        pk.x = pack_bf2(o.x, o.y);
        pk.y = pack_bf2(o.z, o.w);
        *(uint2*)(H1b + (size_t)node * 64 + li * 2) = pk;
    }
}

// Layer 2: *dinv, + b2, then JK max with H1 (in-place bf16 H1 -> JK)
__global__ __launch_bounds__(256) void agg2_k(
    const unsigned* __restrict__ H, const int* __restrict__ el,
    const int* __restrict__ offsets, const int* __restrict__ counts,
    const float* __restrict__ dinv, const float* __restrict__ b2,
    unsigned* __restrict__ H1b, int n) {
    int lane = threadIdx.x & 63;
    int li = lane & 31;
    int half = lane >> 5;
    int node = blockIdx.x * 4 + (threadIdx.x >> 6);
    if (node >= n) return;
    float4 acc = agg_core((const uint2*)H, el, offsets[node], counts[node],
                          node, n, li, half);
    if (half == 0) {
        float dv = dinv[node];
        int f0 = li * 4;
        float4 bb = *(const float4*)(b2 + f0);
        uint2* p = (uint2*)(H1b + (size_t)node * 64 + li * 2);
        uint2 hv = *p;
        float2 ha = unpack_bf2(hv.x);
        float2 hb = unpack_bf2(hv.y);
        float4 o;
        o.x = fmaxf(ha.x, acc.x * dv + bb.x);
        o.y = fmaxf(ha.y, acc.y * dv + bb.y);
        o.z = fmaxf(hb.x, acc.z * dv + bb.z);
        o.w = fmaxf(hb.y, acc.w * dv + bb.w);
        uint2 pk;
        pk.x = pack_bf2(o.x, o.y);
        pk.y = pack_bf2(o.z, o.w);
        *p = pk;
    }
}

// ---------------------------------------------------------------------------
// Head: tiled GEMM (64 nodes x 48 cols, K=128) + fused log_softmax.
// JK input is packed bf16 [n][64 uints].
// ---------------------------------------------------------------------------
__global__ __launch_bounds__(256) void head_k(const unsigned* __restrict__ JKb,
                                              const float* __restrict__ Wf,
                                              const float* __restrict__ bf,
                                              float* __restrict__ out, int n) {
    __shared__ __align__(16) float Bs[48 * 132];  // [col][k], stride 132
    __shared__ __align__(16) float As[64 * 36];   // [row][k-in-panel], stride 36
    int tid = threadIdx.x;
    for (int p = tid; p < 47 * 32; p += 256) {
        int c = p >> 5;          // 0..46
        int k0 = (p & 31) << 2;  // 0,4,...,124
        float4 v;
        v.x = Wf[(size_t)(k0 + 0) * DOUT + c];
        v.y = Wf[(size_t)(k0 + 1) * DOUT + c];
        v.z = Wf[(size_t)(k0 + 2) * DOUT + c];
        v.w = Wf[(size_t)(k0 + 3) * DOUT + c];
        *(float4*)(&Bs[c * 132 + k0]) = v;
    }
    int tx = tid & 15;   // col group: cols [3*tx, 3*tx+3)
    int ty = tid >> 4;   // row group: rows [4*ty, 4*ty+4)
    int node0 = blockIdx.x * 64;

    float acc[4][3];
#pragma unroll
    for (int i = 0; i < 4; i++)
#pragma unroll
        for (int j = 0; j < 3; j++) acc[i][j] = 0.f;

    for (int kk = 0; kk < 128; kk += 32) {
        __syncthreads();
        for (int l = tid; l < 512; l += 256) {
            int r = l >> 3;
            int c4 = (l & 7) << 2;
            int row = node0 + r;
            float4 v = make_float4(0.f, 0.f, 0.f, 0.f);
            if (row < n) {
                uint2 u = *(const uint2*)(JKb + (size_t)row * 64 + ((kk + c4) >> 1));
                float2 f0 = unpack_bf2(u.x);
                float2 f1 = unpack_bf2(u.y);
                v = make_float4(f0.x, f0.y, f1.x, f1.y);
            }
            *(float4*)(&As[r * 36 + c4]) = v;
        }
        __syncthreads();
#pragma unroll
        for (int k4 = 0; k4 < 32; k4 += 4) {
            float4 a0 = *(const float4*)(&As[(ty * 4 + 0) * 36 + k4]);
            float4 a1 = *(const float4*)(&As[(ty * 4 + 1) * 36 + k4]);
            float4 a2 = *(const float4*)(&As[(ty * 4 + 2) * 36 + k4]);
            float4 a3 = *(const float4*)(&As[(ty * 4 + 3) * 36 + k4]);
            float4 b0 = *(const float4*)(&Bs[(tx * 3 + 0) * 132 + kk + k4]);
            float4 b1 = *(const float4*)(&Bs[(tx * 3 + 1) * 132 + kk + k4]);
            float4 b2 = *(const float4*)(&Bs[(tx * 3 + 2) * 132 + kk + k4]);
#define DOT_ROW(i, a)                                                        \
            acc[i][0] = fmaf(a.x, b0.x, acc[i][0]);                          \
            acc[i][0] = fmaf(a.y, b0.y, acc[i][0]);                          \
            acc[i][0] = fmaf(a.z, b0.z, acc[i][0]);                          \
            acc[i][0] = fmaf(a.w, b0.w, acc[i][0]);                          \
            acc[i][1] = fmaf(a.x, b1.x, acc[i][1]);                          \
            acc[i][1] = fmaf(a.y, b1.y, acc[i][1]);                          \
            acc[i][1] = fmaf(a.z, b1.z, acc[i][1]);                          \
            acc[i][1] = fmaf(a.w, b1.w, acc[i][1]);                          \
            acc[i][2] = fmaf(a.x, b2.x, acc[i][2]);                          \
            acc[i][2] = fmaf(a.y, b2.y, acc[i][2]);                          \
            acc[i][2] = fmaf(a.z, b2.z, acc[i][2]);                          \
            acc[i][2] = fmaf(a.w, b2.w, acc[i][2]);
            DOT_ROW(0, a0)
            DOT_ROW(1, a1)
            DOT_ROW(2, a2)
            DOT_ROW(3, a3)
#undef DOT_ROW
        }
    }

    float bfv[3];
#pragma unroll
    for (int j = 0; j < 3; j++) {
        int c = tx * 3 + j;
        bfv[j] = (c < DOUT) ? bf[c] : 0.f;
    }
#pragma unroll
    for (int i = 0; i < 4; i++) {
        int node = node0 + ty * 4 + i;
        float l0 = acc[i][0] + bfv[0];
        float l1 = acc[i][1] + bfv[1];
        float l2 = acc[i][2] + bfv[2];
        bool v2ok = (tx * 3 + 2) < DOUT;  // only col 47 (tx=15,j=2) invalid
        float m = fmaxf(l0, l1);
        if (v2ok) m = fmaxf(m, l2);
        for (int off = 8; off >= 1; off >>= 1) m = fmaxf(m, __shfl_xor(m, off));
        float s = expf(l0 - m) + expf(l1 - m) + (v2ok ? expf(l2 - m) : 0.f);
        for (int off = 8; off >= 1; off >>= 1) s += __shfl_xor(s, off);
        float ls = m + logf(s);
        if (node < n) {
            float* o = out + (size_t)node * DOUT + tx * 3;
            o[0] = l0 - ls;
            o[1] = l1 - ls;
            if (v2ok) o[2] = l2 - ls;
        }
    }
}

// ---------------------------------------------------------------------------
extern "C" void kernel_launch(void* const* d_in, const int* in_sizes, int n_in,
                              void* d_out, int out_size, void* d_ws, size_t ws_size,
                              hipStream_t stream) {
    const float* x     = (const float*)d_in[0];
    const int*   ei    = (const int*)d_in[1];
    const float* W1    = (const float*)d_in[2];
    const float* b1    = (const float*)d_in[3];
    const float* gamma = (const float*)d_in[4];
    const float* beta  = (const float*)d_in[5];
    const float* mean  = (const float*)d_in[6];
    const float* var   = (const float*)d_in[7];
    const float* W2    = (const float*)d_in[8];
    const float* b2    = (const float*)d_in[9];
    const float* Wf    = (const float*)d_in[10];
    const float* bf    = (const float*)d_in[11];
    float* out = (float*)d_out;

    int N_ = in_sizes[0] / 128;
    int E_ = in_sizes[1] / 2;
    const int* src = ei;
    const int* dst = ei + E_;

    char* ws = (char*)d_ws;
    unsigned* bufA = (unsigned*)ws; ws += (size_t)(N_ + 1) * 64 * 4;  // bf16 table + sentinel row
    unsigned* h1b  = (unsigned*)ws; ws += (size_t)N_ * 64 * 4;        // bf16 h1 / JK
    int*   counts  = (int*)ws;    ws += (size_t)N_ * 4;
    int*   offsets = (int*)ws;    ws += (size_t)N_ * 4;
    float* dinv    = (float*)ws;  ws += (size_t)N_ * 4;
    int*   rank    = (int*)ws;    ws += (size_t)E_ * 4;
    // padded edge list (4-B src indices): sum((c+7)&~7) <= E+7N; +128 tail
    int*   el      = (int*)ws;    ws += ((size_t)E_ + 7 * (size_t)N_ + 128) * 4;
    int*   bsums   = (int*)ws;    ws += 1024 * 4;
    unsigned* W1b  = (unsigned*)ws; ws += 128 * 64 * 4;               // bf16 W^T [n][k]
    unsigned* W2b  = (unsigned*)ws; ws += 128 * 64 * 4;

    int nb = (N_ + 1023) / 1024;
    int gemmBlocks = (N_ + 63) / 64;
    int edgeBlocks = (E_ + 1023) / 1024;  // 4 edges/thread

    prep_k<<<2 + (N_ + 255) / 256, 256, 0, stream>>>(W1, W2, W1b, W2b,
                                                     counts, bufA, N_);
    count_rank_k<<<edgeBlocks, 256, 0, stream>>>(dst, counts, rank, E_);
    scan1_k<<<nb, 256, 0, stream>>>(counts, offsets, bsums, N_);
    scan2_k<<<1, 128, 0, stream>>>(bsums, nb, el, N_);
    finalize_k<<<(N_ + 255) / 256, 256, 0, stream>>>(offsets, dinv,
                                                     counts, bsums, el, N_);
    scatter_k<<<edgeBlocks, 256, 0, stream>>>(src, dst, rank, offsets, el, E_);

    // layer 1 (pre-scaled table)
    gemm_mfma_k<<<gemmBlocks, 256, 0, stream>>>(x, W1b, dinv, bufA, N_);
    agg1_k<<<(N_ + 3) / 4, 256, 0, stream>>>(bufA, el, offsets, counts, dinv,
                                             b1, gamma, beta, mean, var, h1b, N_);
    // layer 2 (bf16 A -> single-mfma gemm, pre-scaled table)
    gemm_bf16_k<<<gemmBlocks, 256, 0, stream>>>(h1b, W2b, dinv, bufA, N_);
    agg2_k<<<(N_ + 3) / 4, 256, 0, stream>>>(bufA, el, offsets, counts, dinv,
                                             b2, h1b, N_);
    // head: h1b now holds jk = max(h1, h2) in bf16; 64 nodes per block
    head_k<<<(N_ + 63) / 64, 256, 0, stream>>>(h1b, Wf, bf, out, N_);
}

// Round 3
// 421.244 us; speedup vs baseline: 1.0532x; 1.0532x over previous
//
#include <hip/hip_runtime.h>
#include <math.h>

// Problem constants (from reference): N=100000, E=1600000, D_IN=D_H=128, D_OUT=47
#define DH 128
#define DOUT 47
#define BN_EPS 1e-5f

typedef __attribute__((ext_vector_type(8))) short short8;
typedef __attribute__((ext_vector_type(4))) float float4v;
typedef __attribute__((ext_vector_type(2))) float float2v;

// ---------------------------------------------------------------------------
// bf16 pack/unpack (RNE).
// ---------------------------------------------------------------------------
__device__ __forceinline__ unsigned bf16_rne(float f) {
    unsigned u = __float_as_uint(f);
    return (u + 0x7fffu + ((u >> 16) & 1u)) >> 16;
}
__device__ __forceinline__ unsigned pack_bf2(float a, float b) {
    return (bf16_rne(a) & 0xffffu) | (bf16_rne(b) << 16);
}
__device__ __forceinline__ float2 unpack_bf2(unsigned u) {
    return make_float2(__uint_as_float(u << 16),
                       __uint_as_float(u & 0xffff0000u));
}

// packed accumulate: a.(lo,hi) += (bf16lo(u), bf16hi(u)) via v_pk_add_f32.
// Two independent IEEE f32 adds -> bitwise-identical to the scalar pair.
__device__ __forceinline__ void bf2_acc(float2v& a, unsigned u) {
    float2v f;
    f.x = __uint_as_float(u << 16);
    f.y = __uint_as_float(u & 0xffff0000u);
    asm("v_pk_add_f32 %0, %0, %1" : "+v"(a) : "v"(f));
}

// ---------------------------------------------------------------------------
// Pre-scaled-table GCN: table row g[s] = dinv[s] * (X@W)[s]; edge record is a
// bare 4-B src index; pads/tail point at zeroed sentinel row N.
// ---------------------------------------------------------------------------

// prep: block 0 -> W1 transpose+bf16 (+ zero sentinel row of bufA),
//       block 1 -> W2, blocks >=2 -> zero counts.
__global__ __launch_bounds__(256) void prep_k(const float* __restrict__ W1,
                                              const float* __restrict__ W2,
                                              unsigned* __restrict__ W1b,
                                              unsigned* __restrict__ W2b,
                                              int* __restrict__ counts,
                                              unsigned* __restrict__ bufA, int n) {
    int tid = threadIdx.x;
    if (blockIdx.x >= 2) {
        int i = (blockIdx.x - 2) * 256 + tid;
        if (i < n) counts[i] = 0;
        return;
    }
    const float* W = blockIdx.x ? W2 : W1;
    unsigned* Wb = blockIdx.x ? W2b : W1b;
    if (blockIdx.x == 0 && tid < 64) bufA[(size_t)n * 64 + tid] = 0;  // sentinel row
    for (int p = tid; p < 128 * 32; p += 256) {
        int nn = p >> 5;
        int k0 = (p & 31) << 2;
        float f0 = W[(size_t)(k0 + 0) * 128 + nn];
        float f1 = W[(size_t)(k0 + 1) * 128 + nn];
        float f2 = W[(size_t)(k0 + 2) * 128 + nn];
        float f3 = W[(size_t)(k0 + 3) * 128 + nn];
        uint2 v;
        v.x = pack_bf2(f0, f1);
        v.y = pack_bf2(f2, f3);
        *(uint2*)(Wb + (size_t)nn * 64 + (k0 >> 1)) = v;
    }
}

// count_rank v2: 8 edges/thread (probe: tests whether the 23 G-atomic/s rate
// is a device ceiling or an issue-side limit; logic otherwise identical).
__global__ __launch_bounds__(256) void count_rank_k(const int* __restrict__ dst,
                                                    int* __restrict__ counts,
                                                    int* __restrict__ rank, int e) {
    int i0 = (blockIdx.x * 256 + threadIdx.x) * 8;
    if (i0 + 8 <= e) {
        int4 d4 = *(const int4*)(dst + i0);
        int4 e4 = *(const int4*)(dst + i0 + 4);
        int4 r4, s4;
        r4.x = atomicAdd(&counts[d4.x], 1);
        r4.y = atomicAdd(&counts[d4.y], 1);
        r4.z = atomicAdd(&counts[d4.z], 1);
        r4.w = atomicAdd(&counts[d4.w], 1);
        s4.x = atomicAdd(&counts[e4.x], 1);
        s4.y = atomicAdd(&counts[e4.y], 1);
        s4.z = atomicAdd(&counts[e4.z], 1);
        s4.w = atomicAdd(&counts[e4.w], 1);
        *(int4*)(rank + i0) = r4;
        *(int4*)(rank + i0 + 4) = s4;
    } else {
        for (int i = i0; i < e; i++) rank[i] = atomicAdd(&counts[dst[i]], 1);
    }
}

// scan1 scans PADDED counts ((c+7)&~7).
__global__ __launch_bounds__(256) void scan1_k(const int* __restrict__ counts,
                                               int* __restrict__ offsets,
                                               int* __restrict__ blocksums, int n) {
    __shared__ int sd[256];
    int tid = threadIdx.x;
    int base = blockIdx.x * 1024 + tid * 4;
    int v0 = (base + 0 < n) ? ((counts[base + 0] + 7) & ~7) : 0;
    int v1 = (base + 1 < n) ? ((counts[base + 1] + 7) & ~7) : 0;
    int v2 = (base + 2 < n) ? ((counts[base + 2] + 7) & ~7) : 0;
    int v3 = (base + 3 < n) ? ((counts[base + 3] + 7) & ~7) : 0;
    int tsum = v0 + v1 + v2 + v3;
    sd[tid] = tsum;
    __syncthreads();
    for (int off = 1; off < 256; off <<= 1) {
        int x = (tid >= off) ? sd[tid - off] : 0;
        __syncthreads();
        sd[tid] += x;
        __syncthreads();
    }
    if (tid == 255) blocksums[blockIdx.x] = sd[255];
    int run = sd[tid] - tsum;
    if (base + 0 < n) offsets[base + 0] = run;  run += v0;
    if (base + 1 < n) offsets[base + 1] = run;  run += v1;
    if (base + 2 < n) offsets[base + 2] = run;  run += v2;
    if (base + 3 < n) offsets[base + 3] = run;
}

// scan2: exclusive scan of block sums + write el tail sentinels (row n) so
// the agg pipeline's phantom prefetches always read valid row indices.
__global__ __launch_bounds__(128) void scan2_k(int* __restrict__ blocksums, int nb,
                                               int* __restrict__ el, int n) {
    __shared__ int sd[128];
    int tid = threadIdx.x;
    int v = (tid < nb) ? blocksums[tid] : 0;
    sd[tid] = v;
    __syncthreads();
    for (int off = 1; off < 128; off <<= 1) {
        int x = (tid >= off) ? sd[tid - off] : 0;
        __syncthreads();
        sd[tid] += x;
        __syncthreads();
    }
    if (tid < nb) blocksums[tid] = sd[tid] - v;  // exclusive
    int total = sd[127];                         // total padded edges
    if (tid < 96) el[total + tid] = n;           // sentinel tail
}

// finalize: padded offsets, dinv, pad records = sentinel row n.
__global__ void finalize_k(int* __restrict__ offsets,
                           float* __restrict__ dinv, const int* __restrict__ counts,
                           const int* __restrict__ blocksums,
                           int* __restrict__ el, int n) {
    int i = blockIdx.x * 256 + threadIdx.x;
    if (i >= n) return;
    int o = offsets[i] + blocksums[i >> 10];
    offsets[i] = o;
    int c = counts[i];
    dinv[i] = rsqrtf((float)(c + 1));  // +1 self-loop; deg>=1 always
    int cP = (c + 7) & ~7;
    for (int j = o + c; j < o + cP; ++j) el[j] = n;  // pad -> zero row
}

// scatter: atomic-free, 4-B records (src only).
__global__ __launch_bounds__(256) void scatter_k(const int* __restrict__ src,
                                                 const int* __restrict__ dst,
                                                 const int* __restrict__ rank,
                                                 const int* __restrict__ offsets,
                                                 int* __restrict__ el, int e) {
    int i0 = (blockIdx.x * 256 + threadIdx.x) * 4;
    if (i0 + 4 <= e) {
        int4 s4 = *(const int4*)(src + i0);
        int4 d4 = *(const int4*)(dst + i0);
        int4 r4 = *(const int4*)(rank + i0);
        el[offsets[d4.x] + r4.x] = s4.x;
        el[offsets[d4.y] + r4.y] = s4.y;
        el[offsets[d4.z] + r4.z] = s4.z;
        el[offsets[d4.w] + r4.w] = s4.w;
    } else {
        for (int i = i0; i < e; i++) el[offsets[dst[i]] + rank[i]] = src[i];
    }
}

// ---------------------------------------------------------------------------
// MFMA GEMM (layer 1): A fp32 -> bf16 in-register (single mfma per tile;
// x-quantization is the same error class as the accepted bf16 roundings),
// W bf16 [n][k] in LDS. Output row scaled by dinv[row], packed bf16.
// ---------------------------------------------------------------------------
__global__ __launch_bounds__(256) void gemm_mfma_k(const float* __restrict__ A,
                                                   const unsigned* __restrict__ Wb,
                                                   const float* __restrict__ dinv,
                                                   unsigned* __restrict__ Cb, int M) {
    __shared__ ushort Bl[128 * 136];
    int tid = threadIdx.x;
    {
        unsigned* Bu = (unsigned*)Bl;
        for (int q = tid; q < 128 * 16; q += 256) {
            int row = q >> 4;
            int c = (q & 15) << 2;
            uint4 v = *(const uint4*)(Wb + (size_t)row * 64 + c);
            *(uint4*)(Bu + (size_t)row * 68 + c) = v;
        }
    }
    __syncthreads();

    int lane = tid & 63;
    int wv = tid >> 6;
    int quad = lane >> 4;
    int l15 = lane & 15;
    int r0 = blockIdx.x * 64 + wv * 16;
    int mload = r0 + l15;
    if (mload > M - 1) mload = M - 1;
    const float* Ar = A + (size_t)mload * 128 + quad * 8;

    float4v acc[8];
#pragma unroll
    for (int t = 0; t < 8; t++) acc[t] = (float4v){0.f, 0.f, 0.f, 0.f};

    for (int kp = 0; kp < 4; ++kp) {
        float4 a0 = *(const float4*)(Ar + kp * 32);
        float4 a1 = *(const float4*)(Ar + kp * 32 + 4);
        float af[8] = {a0.x, a0.y, a0.z, a0.w, a1.x, a1.y, a1.z, a1.w};
        short8 av;
#pragma unroll
        for (int j = 0; j < 8; j++) av[j] = (short)bf16_rne(af[j]);
        int kb = kp * 32 + quad * 8;
#pragma unroll
        for (int nt = 0; nt < 8; nt++) {
            short8 b8 = *(const short8*)(&Bl[(size_t)(nt * 16 + l15) * 136 + kb]);
            acc[nt] = __builtin_amdgcn_mfma_f32_16x16x32_bf16(av, b8, acc[nt], 0, 0, 0);
        }
    }

    ushort* Cu = (ushort*)Cb;
#pragma unroll
    for (int r = 0; r < 4; r++) {
        int row = r0 + quad * 4 + r;
        if (row < M) {
            float dv = dinv[row];
#pragma unroll
            for (int nt = 0; nt < 8; nt++) {
                Cu[(size_t)row * 128 + nt * 16 + l15] =
                    (ushort)bf16_rne(acc[nt][r] * dv);
            }
        }
    }
}

// ---------------------------------------------------------------------------
// MFMA GEMM (layer 2): A already bf16 packed -> single mfma per tile.
// Output row scaled by dinv[row].
// ---------------------------------------------------------------------------
__global__ __launch_bounds__(256) void gemm_bf16_k(const unsigned* __restrict__ Ab,
                                                   const unsigned* __restrict__ Wb,
                                                   const float* __restrict__ dinv,
                                                   unsigned* __restrict__ Cb, int M) {
    __shared__ ushort Bl[128 * 136];
    int tid = threadIdx.x;
    {
        unsigned* Bu = (unsigned*)Bl;
        for (int q = tid; q < 128 * 16; q += 256) {
            int row = q >> 4;
            int c = (q & 15) << 2;
            uint4 v = *(const uint4*)(Wb + (size_t)row * 64 + c);
            *(uint4*)(Bu + (size_t)row * 68 + c) = v;
        }
    }
    __syncthreads();

    int lane = tid & 63;
    int wv = tid >> 6;
    int quad = lane >> 4;
    int l15 = lane & 15;
    int r0 = blockIdx.x * 64 + wv * 16;
    int mload = r0 + l15;
    if (mload > M - 1) mload = M - 1;
    const unsigned* Ar = Ab + (size_t)mload * 64 + quad * 4;

    float4v acc[8];
#pragma unroll
    for (int t = 0; t < 8; t++) acc[t] = (float4v){0.f, 0.f, 0.f, 0.f};

    for (int kp = 0; kp < 4; ++kp) {
        uint4 a4 = *(const uint4*)(Ar + kp * 16);
        short8 av;
        av[0] = (short)(a4.x & 0xffff); av[1] = (short)(a4.x >> 16);
        av[2] = (short)(a4.y & 0xffff); av[3] = (short)(a4.y >> 16);
        av[4] = (short)(a4.z & 0xffff); av[5] = (short)(a4.z >> 16);
        av[6] = (short)(a4.w & 0xffff); av[7] = (short)(a4.w >> 16);
        int kb = kp * 32 + quad * 8;
#pragma unroll
        for (int nt = 0; nt < 8; nt++) {
            short8 b8 = *(const short8*)(&Bl[(size_t)(nt * 16 + l15) * 136 + kb]);
            acc[nt] = __builtin_amdgcn_mfma_f32_16x16x32_bf16(av, b8, acc[nt], 0, 0, 0);
        }
    }

    ushort* Cu = (ushort*)Cb;
#pragma unroll
    for (int r = 0; r < 4; r++) {
        int row = r0 + quad * 4 + r;
        if (row < M) {
            float dv = dinv[row];
#pragma unroll
            for (int nt = 0; nt < 8; nt++) {
                Cu[(size_t)row * 128 + nt * 16 + l15] =
                    (ushort)bf16_rne(acc[nt][r] * dv);
            }
        }
    }
}

// ---------------------------------------------------------------------------
// Aggregation core v5b: the proven 2-deep rotating pipeline (v5, 69 us, no
// spill), with the ONLY change being v_pk_add_f32 packed accumulation
// (1:1 swap for the scalar add pairs; bitwise-identical summation order).
// Phantom prefetches past a node's list read the next node's rows — these
// act as cross-wave prefetch for the adjacent wave in the same block, and
// the sentinel tail guarantees they are valid row indices.
// Returns UNSCALED sum incl. self row; caller multiplies by dinv[node].
// ---------------------------------------------------------------------------
__device__ __forceinline__ float4 agg_core(const uint2* __restrict__ Hu2,
                                           const int* __restrict__ el,
                                           int start, int cnt, int node,
                                           int li, int half) {
    float2v a01 = {0.f, 0.f};
    float2v a23 = {0.f, 0.f};
    int groups = ((cnt + 7) & ~7) >> 3;
    if (groups > 0) {
        const int* p = el + start + half * 4;
        int4 r = *(const int4*)p;
        uint2 c0 = Hu2[(size_t)r.x * 32 + li];
        uint2 c1 = Hu2[(size_t)r.y * 32 + li];
        uint2 c2 = Hu2[(size_t)r.z * 32 + li];
        uint2 c3 = Hu2[(size_t)r.w * 32 + li];
        int4 rn = *(const int4*)(p + 8);
        for (int g = 0; g < groups; ++g) {
            // in-flight: features for group g+1
            uint2 n0 = Hu2[(size_t)rn.x * 32 + li];
            uint2 n1 = Hu2[(size_t)rn.y * 32 + li];
            uint2 n2 = Hu2[(size_t)rn.z * 32 + li];
            uint2 n3 = Hu2[(size_t)rn.w * 32 + li];
            // recs for group g+2
            int4 r2 = *(const int4*)(p + 8 * (g + 2));
            // accumulate group g (packed adds; same order as scalar version)
            bf2_acc(a01, c0.x); bf2_acc(a23, c0.y);
            bf2_acc(a01, c1.x); bf2_acc(a23, c1.y);
            bf2_acc(a01, c2.x); bf2_acc(a23, c2.y);
            bf2_acc(a01, c3.x); bf2_acc(a23, c3.y);
            c0 = n0; c1 = n1; c2 = n2; c3 = n3;
            rn = r2;
        }
    }
    float4 acc = make_float4(a01.x, a01.y, a23.x, a23.y);
    acc.x += __shfl_xor(acc.x, 32);
    acc.y += __shfl_xor(acc.y, 32);
    acc.z += __shfl_xor(acc.z, 32);
    acc.w += __shfl_xor(acc.w, 32);
    uint2 sv = Hu2[(size_t)node * 32 + li];  // self row (pre-scaled by dinv[node])
    float2 s0 = unpack_bf2(sv.x);
    float2 s1 = unpack_bf2(sv.y);
    acc.x += s0.x; acc.y += s0.y; acc.z += s1.x; acc.w += s1.y;
    return acc;
}

// Layer 1: *dinv, + b1, BN(eval), ReLU -> H1 packed bf16
__global__ __launch_bounds__(256) void agg1_k(
    const unsigned* __restrict__ H, const int* __restrict__ el,
    const int* __restrict__ offsets, const int* __restrict__ counts,
    const float* __restrict__ dinv, const float* __restrict__ b1,
    const float* __restrict__ gamma, const float* __restrict__ beta,
    const float* __restrict__ mean, const float* __restrict__ var,
    unsigned* __restrict__ H1b, int n) {
    int lane = threadIdx.x & 63;
    int li = lane & 31;
    int half = lane >> 5;
    int node = blockIdx.x * 4 + (threadIdx.x >> 6);
    if (node >= n) return;
    float4 acc = agg_core((const uint2*)H, el, offsets[node], counts[node],
                          node, li, half);
    if (half == 0) {
        float dv = dinv[node];
        int f0 = li * 4;
        float4 bb = *(const float4*)(b1 + f0);
        float4 mm = *(const float4*)(mean + f0);
        float4 vv = *(const float4*)(var + f0);
        float4 gg = *(const float4*)(gamma + f0);
        float4 be = *(const float4*)(beta + f0);
        float4 o;
        o.x = fmaxf((acc.x * dv + bb.x - mm.x) * rsqrtf(vv.x + BN_EPS) * gg.x + be.x, 0.f);
        o.y = fmaxf((acc.y * dv + bb.y - mm.y) * rsqrtf(vv.y + BN_EPS) * gg.y + be.y, 0.f);
        o.z = fmaxf((acc.z * dv + bb.z - mm.z) * rsqrtf(vv.z + BN_EPS) * gg.z + be.z, 0.f);
        o.w = fmaxf((acc.w * dv + bb.w - mm.w) * rsqrtf(vv.w + BN_EPS) * gg.w + be.w, 0.f);
        uint2 pk;
        pk.x = pack_bf2(o.x, o.y);
        pk.y = pack_bf2(o.z, o.w);
        *(uint2*)(H1b + (size_t)node * 64 + li * 2) = pk;
    }
}

// Layer 2: *dinv, + b2, then JK max with H1 (in-place bf16 H1 -> JK)
__global__ __launch_bounds__(256) void agg2_k(
    const unsigned* __restrict__ H, const int* __restrict__ el,
    const int* __restrict__ offsets, const int* __restrict__ counts,
    const float* __restrict__ dinv, const float* __restrict__ b2,
    unsigned* __restrict__ H1b, int n) {
    int lane = threadIdx.x & 63;
    int li = lane & 31;
    int half = lane >> 5;
    int node = blockIdx.x * 4 + (threadIdx.x >> 6);
    if (node >= n) return;
    float4 acc = agg_core((const uint2*)H, el, offsets[node], counts[node],
                          node, li, half);
    if (half == 0) {
        float dv = dinv[node];
        int f0 = li * 4;
        float4 bb = *(const float4*)(b2 + f0);
        uint2* p = (uint2*)(H1b + (size_t)node * 64 + li * 2);
        uint2 hv = *p;
        float2 ha = unpack_bf2(hv.x);
        float2 hb = unpack_bf2(hv.y);
        float4 o;
        o.x = fmaxf(ha.x, acc.x * dv + bb.x);
        o.y = fmaxf(ha.y, acc.y * dv + bb.y);
        o.z = fmaxf(hb.x, acc.z * dv + bb.z);
        o.w = fmaxf(hb.y, acc.w * dv + bb.w);
        uint2 pk;
        pk.x = pack_bf2(o.x, o.y);
        pk.y = pack_bf2(o.z, o.w);
        *p = pk;
    }
}

// ---------------------------------------------------------------------------
// Head: tiled GEMM (64 nodes x 48 cols, K=128) + fused log_softmax.
// JK input is packed bf16 [n][64 uints].
// ---------------------------------------------------------------------------
__global__ __launch_bounds__(256) void head_k(const unsigned* __restrict__ JKb,
                                              const float* __restrict__ Wf,
                                              const float* __restrict__ bf,
                                              float* __restrict__ out, int n) {
    __shared__ __align__(16) float Bs[48 * 132];  // [col][k], stride 132
    __shared__ __align__(16) float As[64 * 36];   // [row][k-in-panel], stride 36
    int tid = threadIdx.x;
    for (int p = tid; p < 47 * 32; p += 256) {
        int c = p >> 5;          // 0..46
        int k0 = (p & 31) << 2;  // 0,4,...,124
        float4 v;
        v.x = Wf[(size_t)(k0 + 0) * DOUT + c];
        v.y = Wf[(size_t)(k0 + 1) * DOUT + c];
        v.z = Wf[(size_t)(k0 + 2) * DOUT + c];
        v.w = Wf[(size_t)(k0 + 3) * DOUT + c];
        *(float4*)(&Bs[c * 132 + k0]) = v;
    }
    int tx = tid & 15;   // col group: cols [3*tx, 3*tx+3)
    int ty = tid >> 4;   // row group: rows [4*ty, 4*ty+4)
    int node0 = blockIdx.x * 64;

    float acc[4][3];
#pragma unroll
    for (int i = 0; i < 4; i++)
#pragma unroll
        for (int j = 0; j < 3; j++) acc[i][j] = 0.f;

    for (int kk = 0; kk < 128; kk += 32) {
        __syncthreads();
        for (int l = tid; l < 512; l += 256) {
            int r = l >> 3;
            int c4 = (l & 7) << 2;
            int row = node0 + r;
            float4 v = make_float4(0.f, 0.f, 0.f, 0.f);
            if (row < n) {
                uint2 u = *(const uint2*)(JKb + (size_t)row * 64 + ((kk + c4) >> 1));
                float2 f0 = unpack_bf2(u.x);
                float2 f1 = unpack_bf2(u.y);
                v = make_float4(f0.x, f0.y, f1.x, f1.y);
            }
            *(float4*)(&As[r * 36 + c4]) = v;
        }
        __syncthreads();
#pragma unroll
        for (int k4 = 0; k4 < 32; k4 += 4) {
            float4 a0 = *(const float4*)(&As[(ty * 4 + 0) * 36 + k4]);
            float4 a1 = *(const float4*)(&As[(ty * 4 + 1) * 36 + k4]);
            float4 a2 = *(const float4*)(&As[(ty * 4 + 2) * 36 + k4]);
            float4 a3 = *(const float4*)(&As[(ty * 4 + 3) * 36 + k4]);
            float4 b0 = *(const float4*)(&Bs[(tx * 3 + 0) * 132 + kk + k4]);
            float4 b1 = *(const float4*)(&Bs[(tx * 3 + 1) * 132 + kk + k4]);
            float4 b2 = *(const float4*)(&Bs[(tx * 3 + 2) * 132 + kk + k4]);
#define DOT_ROW(i, a)                                                        \
            acc[i][0] = fmaf(a.x, b0.x, acc[i][0]);                          \
            acc[i][0] = fmaf(a.y, b0.y, acc[i][0]);                          \
            acc[i][0] = fmaf(a.z, b0.z, acc[i][0]);                          \
            acc[i][0] = fmaf(a.w, b0.w, acc[i][0]);                          \
            acc[i][1] = fmaf(a.x, b1.x, acc[i][1]);                          \
            acc[i][1] = fmaf(a.y, b1.y, acc[i][1]);                          \
            acc[i][1] = fmaf(a.z, b1.z, acc[i][1]);                          \
            acc[i][1] = fmaf(a.w, b1.w, acc[i][1]);                          \
            acc[i][2] = fmaf(a.x, b2.x, acc[i][2]);                          \
            acc[i][2] = fmaf(a.y, b2.y, acc[i][2]);                          \
            acc[i][2] = fmaf(a.z, b2.z, acc[i][2]);                          \
            acc[i][2] = fmaf(a.w, b2.w, acc[i][2]);
            DOT_ROW(0, a0)
            DOT_ROW(1, a1)
            DOT_ROW(2, a2)
            DOT_ROW(3, a3)
#undef DOT_ROW
        }
    }

    float bfv[3];
#pragma unroll
    for (int j = 0; j < 3; j++) {
        int c = tx * 3 + j;
        bfv[j] = (c < DOUT) ? bf[c] : 0.f;
    }
#pragma unroll
    for (int i = 0; i < 4; i++) {
        int node = node0 + ty * 4 + i;
        float l0 = acc[i][0] + bfv[0];
        float l1 = acc[i][1] + bfv[1];
        float l2 = acc[i][2] + bfv[2];
        bool v2ok = (tx * 3 + 2) < DOUT;  // only col 47 (tx=15,j=2) invalid
        float m = fmaxf(l0, l1);
        if (v2ok) m = fmaxf(m, l2);
        for (int off = 8; off >= 1; off >>= 1) m = fmaxf(m, __shfl_xor(m, off));
        float s = expf(l0 - m) + expf(l1 - m) + (v2ok ? expf(l2 - m) : 0.f);
        for (int off = 8; off >= 1; off >>= 1) s += __shfl_xor(s, off);
        float ls = m + logf(s);
        if (node < n) {
            float* o = out + (size_t)node * DOUT + tx * 3;
            o[0] = l0 - ls;
            o[1] = l1 - ls;
            if (v2ok) o[2] = l2 - ls;
        }
    }
}

// ---------------------------------------------------------------------------
extern "C" void kernel_launch(void* const* d_in, const int* in_sizes, int n_in,
                              void* d_out, int out_size, void* d_ws, size_t ws_size,
                              hipStream_t stream) {
    const float* x     = (const float*)d_in[0];
    const int*   ei    = (const int*)d_in[1];
    const float* W1    = (const float*)d_in[2];
    const float* b1    = (const float*)d_in[3];
    const float* gamma = (const float*)d_in[4];
    const float* beta  = (const float*)d_in[5];
    const float* mean  = (const float*)d_in[6];
    const float* var   = (const float*)d_in[7];
    const float* W2    = (const float*)d_in[8];
    const float* b2    = (const float*)d_in[9];
    const float* Wf    = (const float*)d_in[10];
    const float* bf    = (const float*)d_in[11];
    float* out = (float*)d_out;

    int N_ = in_sizes[0] / 128;
    int E_ = in_sizes[1] / 2;
    const int* src = ei;
    const int* dst = ei + E_;

    char* ws = (char*)d_ws;
    unsigned* bufA = (unsigned*)ws; ws += (size_t)(N_ + 1) * 64 * 4;  // bf16 table + sentinel row
    unsigned* h1b  = (unsigned*)ws; ws += (size_t)N_ * 64 * 4;        // bf16 h1 / JK
    int*   counts  = (int*)ws;    ws += (size_t)N_ * 4;
    int*   offsets = (int*)ws;    ws += (size_t)N_ * 4;
    float* dinv    = (float*)ws;  ws += (size_t)N_ * 4;
    int*   rank    = (int*)ws;    ws += (size_t)E_ * 4;
    // padded edge list (4-B src indices): sum((c+7)&~7) <= E+7N; +128 tail
    int*   el      = (int*)ws;    ws += ((size_t)E_ + 7 * (size_t)N_ + 128) * 4;
    int*   bsums   = (int*)ws;    ws += 1024 * 4;
    unsigned* W1b  = (unsigned*)ws; ws += 128 * 64 * 4;               // bf16 W^T [n][k]
    unsigned* W2b  = (unsigned*)ws; ws += 128 * 64 * 4;

    int nb = (N_ + 1023) / 1024;
    int gemmBlocks = (N_ + 63) / 64;
    int edgeBlocks8 = (E_ + 2047) / 2048;  // 8 edges/thread (count_rank)
    int edgeBlocks = (E_ + 1023) / 1024;   // 4 edges/thread (scatter)

    prep_k<<<2 + (N_ + 255) / 256, 256, 0, stream>>>(W1, W2, W1b, W2b,
                                                     counts, bufA, N_);
    count_rank_k<<<edgeBlocks8, 256, 0, stream>>>(dst, counts, rank, E_);
    scan1_k<<<nb, 256, 0, stream>>>(counts, offsets, bsums, N_);
    scan2_k<<<1, 128, 0, stream>>>(bsums, nb, el, N_);
    finalize_k<<<(N_ + 255) / 256, 256, 0, stream>>>(offsets, dinv,
                                                     counts, bsums, el, N_);
    scatter_k<<<edgeBlocks, 256, 0, stream>>>(src, dst, rank, offsets, el, E_);

    // layer 1 (pre-scaled table)
    gemm_mfma_k<<<gemmBlocks, 256, 0, stream>>>(x, W1b, dinv, bufA, N_);
    agg1_k<<<(N_ + 3) / 4, 256, 0, stream>>>(bufA, el, offsets, counts, dinv,
                                             b1, gamma, beta, mean, var, h1b, N_);
    // layer 2 (bf16 A -> single-mfma gemm, pre-scaled table)
    gemm_bf16_k<<<gemmBlocks, 256, 0, stream>>>(h1b, W2b, dinv, bufA, N_);
    agg2_k<<<(N_ + 3) / 4, 256, 0, stream>>>(bufA, el, offsets, counts, dinv,
                                             b2, h1b, N_);
    // head: h1b now holds jk = max(h1, h2) in bf16; 64 nodes per block
    head_k<<<(N_ + 63) / 64, 256, 0, stream>>>(h1b, Wf, bf, out, N_);
}

// Round 4
// 414.195 us; speedup vs baseline: 1.0711x; 1.0170x over previous
//
#include <hip/hip_runtime.h>
#include <math.h>

// Problem constants (from reference): N=100000, E=1600000, D_IN=D_H=128, D_OUT=47
#define DH 128
#define DOUT 47
#define BN_EPS 1e-5f

typedef __attribute__((ext_vector_type(8))) short short8;
typedef __attribute__((ext_vector_type(4))) float float4v;
typedef __attribute__((ext_vector_type(2))) float float2v;

// ---------------------------------------------------------------------------
// bf16 pack/unpack (RNE).
// ---------------------------------------------------------------------------
__device__ __forceinline__ unsigned bf16_rne(float f) {
    unsigned u = __float_as_uint(f);
    return (u + 0x7fffu + ((u >> 16) & 1u)) >> 16;
}
__device__ __forceinline__ unsigned pack_bf2(float a, float b) {
    return (bf16_rne(a) & 0xffffu) | (bf16_rne(b) << 16);
}
__device__ __forceinline__ float2 unpack_bf2(unsigned u) {
    return make_float2(__uint_as_float(u << 16),
                       __uint_as_float(u & 0xffff0000u));
}

// ---------------------------------------------------------------------------
// v5c design: UNSCALED bf16 table (h rows); edge record = src(17b) | q15<<17
// where q15 = round(32767*dinv[src]). Scale applied per-edge via f32 FMA in
// agg (VALU has headroom; proven supply-bound). This breaks the gemm->dinv
// dependency so layer-1 GEMM fuses with the atomic count pass (count's
// 70us shadow hides the GEMM). counts padded to 1 per 64-B line (x16 stride)
// to probe the atomic line-contention hypothesis.
// ---------------------------------------------------------------------------

// prep: block 0 -> W1 transpose+bf16 (+ zero sentinel row of bufA),
//       block 1 -> W2, blocks >=2 -> zero padded counts (N*16 ints).
__global__ __launch_bounds__(256) void prep_k(const float* __restrict__ W1,
                                              const float* __restrict__ W2,
                                              unsigned* __restrict__ W1b,
                                              unsigned* __restrict__ W2b,
                                              int* __restrict__ countsP,
                                              unsigned* __restrict__ bufA, int n) {
    int tid = threadIdx.x;
    if (blockIdx.x >= 2) {
        int i4 = (blockIdx.x - 2) * 256 + tid;     // int4 index
        if (i4 < n * 4) *(int4*)(countsP + (size_t)i4 * 4) = make_int4(0, 0, 0, 0);
        return;
    }
    const float* W = blockIdx.x ? W2 : W1;
    unsigned* Wb = blockIdx.x ? W2b : W1b;
    if (blockIdx.x == 0 && tid < 64) bufA[(size_t)n * 64 + tid] = 0;  // sentinel row
    for (int p = tid; p < 128 * 32; p += 256) {
        int nn = p >> 5;
        int k0 = (p & 31) << 2;
        float f0 = W[(size_t)(k0 + 0) * 128 + nn];
        float f1 = W[(size_t)(k0 + 1) * 128 + nn];
        float f2 = W[(size_t)(k0 + 2) * 128 + nn];
        float f3 = W[(size_t)(k0 + 3) * 128 + nn];
        uint2 v;
        v.x = pack_bf2(f0, f1);
        v.y = pack_bf2(f2, f3);
        *(uint2*)(Wb + (size_t)nn * 64 + (k0 >> 1)) = v;
    }
}

// ---------------------------------------------------------------------------
// FUSED: layer-1 GEMM (unscaled) + count/rank atomics in one kernel.
// Block striping r = bid%3: r==2 -> count chunk (8 edges/thread, padded
// counters); r<2 -> gemm tile gIdx = (bid/3)*2 + r. The count path is
// atomic-throughput-bound with idle VALU/VMEM; the gemm path fills that
// idle hardware inside the count shadow.
// ---------------------------------------------------------------------------
__global__ __launch_bounds__(256) void fused_gc_k(
    const float* __restrict__ A, const unsigned* __restrict__ Wb,
    unsigned* __restrict__ Cb, int M,
    const int* __restrict__ dst, int* __restrict__ countsP,
    int* __restrict__ rank, int e, int gemmBlocks) {
    __shared__ ushort Bl[128 * 136];
    int bid = blockIdx.x;
    int r3 = bid % 3;
    int q3 = bid / 3;
    int tid = threadIdx.x;

    if (r3 == 2) {
        // ---- count/rank part (8 edges/thread, 64-B-strided counters) ----
        int i0 = (q3 * 256 + tid) * 8;
        if (i0 + 8 <= e) {
            int4 d4 = *(const int4*)(dst + i0);
            int4 e4 = *(const int4*)(dst + i0 + 4);
            int4 r4, s4;
            r4.x = atomicAdd(&countsP[(size_t)d4.x * 16], 1);
            r4.y = atomicAdd(&countsP[(size_t)d4.y * 16], 1);
            r4.z = atomicAdd(&countsP[(size_t)d4.z * 16], 1);
            r4.w = atomicAdd(&countsP[(size_t)d4.w * 16], 1);
            s4.x = atomicAdd(&countsP[(size_t)e4.x * 16], 1);
            s4.y = atomicAdd(&countsP[(size_t)e4.y * 16], 1);
            s4.z = atomicAdd(&countsP[(size_t)e4.z * 16], 1);
            s4.w = atomicAdd(&countsP[(size_t)e4.w * 16], 1);
            *(int4*)(rank + i0) = r4;
            *(int4*)(rank + i0 + 4) = s4;
        } else {
            for (int i = i0; i < e; i++)
                rank[i] = atomicAdd(&countsP[(size_t)dst[i] * 16], 1);
        }
        return;
    }

    // ---- gemm part (unscaled output) ----
    int gIdx = q3 * 2 + r3;
    if (gIdx >= gemmBlocks) return;
    {
        unsigned* Bu = (unsigned*)Bl;
        for (int q = tid; q < 128 * 16; q += 256) {
            int row = q >> 4;
            int c = (q & 15) << 2;
            uint4 v = *(const uint4*)(Wb + (size_t)row * 64 + c);
            *(uint4*)(Bu + (size_t)row * 68 + c) = v;
        }
    }
    __syncthreads();

    int lane = tid & 63;
    int wv = tid >> 6;
    int quad = lane >> 4;
    int l15 = lane & 15;
    int r0 = gIdx * 64 + wv * 16;
    int mload = r0 + l15;
    if (mload > M - 1) mload = M - 1;
    const float* Ar = A + (size_t)mload * 128 + quad * 8;

    float4v acc[8];
#pragma unroll
    for (int t = 0; t < 8; t++) acc[t] = (float4v){0.f, 0.f, 0.f, 0.f};

    for (int kp = 0; kp < 4; ++kp) {
        float4 a0 = *(const float4*)(Ar + kp * 32);
        float4 a1 = *(const float4*)(Ar + kp * 32 + 4);
        float af[8] = {a0.x, a0.y, a0.z, a0.w, a1.x, a1.y, a1.z, a1.w};
        short8 av;
#pragma unroll
        for (int j = 0; j < 8; j++) av[j] = (short)bf16_rne(af[j]);
        int kb = kp * 32 + quad * 8;
#pragma unroll
        for (int nt = 0; nt < 8; nt++) {
            short8 b8 = *(const short8*)(&Bl[(size_t)(nt * 16 + l15) * 136 + kb]);
            acc[nt] = __builtin_amdgcn_mfma_f32_16x16x32_bf16(av, b8, acc[nt], 0, 0, 0);
        }
    }

    ushort* Cu = (ushort*)Cb;
#pragma unroll
    for (int r = 0; r < 4; r++) {
        int row = r0 + quad * 4 + r;
        if (row < M) {
#pragma unroll
            for (int nt = 0; nt < 8; nt++) {
                Cu[(size_t)row * 128 + nt * 16 + l15] =
                    (ushort)bf16_rne(acc[nt][r]);
            }
        }
    }
}

// scan1 scans PADDED counts ((c+7)&~7) from strided counters.
__global__ __launch_bounds__(256) void scan1_k(const int* __restrict__ countsP,
                                               int* __restrict__ offsets,
                                               int* __restrict__ blocksums, int n) {
    __shared__ int sd[256];
    int tid = threadIdx.x;
    int base = blockIdx.x * 1024 + tid * 4;
    int v0 = (base + 0 < n) ? ((countsP[(size_t)(base + 0) * 16] + 7) & ~7) : 0;
    int v1 = (base + 1 < n) ? ((countsP[(size_t)(base + 1) * 16] + 7) & ~7) : 0;
    int v2 = (base + 2 < n) ? ((countsP[(size_t)(base + 2) * 16] + 7) & ~7) : 0;
    int v3 = (base + 3 < n) ? ((countsP[(size_t)(base + 3) * 16] + 7) & ~7) : 0;
    int tsum = v0 + v1 + v2 + v3;
    sd[tid] = tsum;
    __syncthreads();
    for (int off = 1; off < 256; off <<= 1) {
        int x = (tid >= off) ? sd[tid - off] : 0;
        __syncthreads();
        sd[tid] += x;
        __syncthreads();
    }
    if (tid == 255) blocksums[blockIdx.x] = sd[255];
    int run = sd[tid] - tsum;
    if (base + 0 < n) offsets[base + 0] = run;  run += v0;
    if (base + 1 < n) offsets[base + 1] = run;  run += v1;
    if (base + 2 < n) offsets[base + 2] = run;  run += v2;
    if (base + 3 < n) offsets[base + 3] = run;
}

// scan2: exclusive scan of block sums + write el tail sentinels (row n, q=0)
// so the agg pipeline's phantom prefetches always read valid row indices.
__global__ __launch_bounds__(128) void scan2_k(int* __restrict__ blocksums, int nb,
                                               int* __restrict__ el, int n) {
    __shared__ int sd[128];
    int tid = threadIdx.x;
    int v = (tid < nb) ? blocksums[tid] : 0;
    sd[tid] = v;
    __syncthreads();
    for (int off = 1; off < 128; off <<= 1) {
        int x = (tid >= off) ? sd[tid - off] : 0;
        __syncthreads();
        sd[tid] += x;
        __syncthreads();
    }
    if (tid < nb) blocksums[tid] = sd[tid] - v;  // exclusive
    int total = sd[127];                         // total padded edges
    if (tid < 96) el[total + tid] = n;           // sentinel tail (q=0, zero row)
}

// finalize: padded offsets, dinv, pad records = sentinel row n (q=0).
__global__ void finalize_k(int* __restrict__ offsets,
                           float* __restrict__ dinv, const int* __restrict__ countsP,
                           const int* __restrict__ blocksums,
                           int* __restrict__ el, int n) {
    int i = blockIdx.x * 256 + threadIdx.x;
    if (i >= n) return;
    int o = offsets[i] + blocksums[i >> 10];
    offsets[i] = o;
    int c = countsP[(size_t)i * 16];
    dinv[i] = rsqrtf((float)(c + 1));  // +1 self-loop; deg>=1 always
    int cP = (c + 7) & ~7;
    for (int j = o + c; j < o + cP; ++j) el[j] = n;  // pad -> zero row, q=0
}

// scatter: atomic-free; record = src(17b) | q15<<17, q15 = round(32767*dinv[src]).
__global__ __launch_bounds__(256) void scatter_k(const int* __restrict__ src,
                                                 const int* __restrict__ dst,
                                                 const int* __restrict__ rank,
                                                 const int* __restrict__ offsets,
                                                 const float* __restrict__ dinv,
                                                 int* __restrict__ el, int e) {
    int i0 = (blockIdx.x * 256 + threadIdx.x) * 4;
    if (i0 + 4 <= e) {
        int4 s4 = *(const int4*)(src + i0);
        int4 d4 = *(const int4*)(dst + i0);
        int4 r4 = *(const int4*)(rank + i0);
        unsigned qx = (unsigned)(dinv[s4.x] * 32767.f + 0.5f);
        unsigned qy = (unsigned)(dinv[s4.y] * 32767.f + 0.5f);
        unsigned qz = (unsigned)(dinv[s4.z] * 32767.f + 0.5f);
        unsigned qw = (unsigned)(dinv[s4.w] * 32767.f + 0.5f);
        el[offsets[d4.x] + r4.x] = (int)((unsigned)s4.x | (qx << 17));
        el[offsets[d4.y] + r4.y] = (int)((unsigned)s4.y | (qy << 17));
        el[offsets[d4.z] + r4.z] = (int)((unsigned)s4.z | (qz << 17));
        el[offsets[d4.w] + r4.w] = (int)((unsigned)s4.w | (qw << 17));
    } else {
        for (int i = i0; i < e; i++) {
            unsigned q = (unsigned)(dinv[src[i]] * 32767.f + 0.5f);
            el[offsets[dst[i]] + rank[i]] = (int)((unsigned)src[i] | (q << 17));
        }
    }
}

// ---------------------------------------------------------------------------
// MFMA GEMM (layer 2): A already bf16 packed -> single mfma per tile.
// Output UNSCALED (per-edge scale lives in the edge records now).
// ---------------------------------------------------------------------------
__global__ __launch_bounds__(256) void gemm_bf16_k(const unsigned* __restrict__ Ab,
                                                   const unsigned* __restrict__ Wb,
                                                   unsigned* __restrict__ Cb, int M) {
    __shared__ ushort Bl[128 * 136];
    int tid = threadIdx.x;
    {
        unsigned* Bu = (unsigned*)Bl;
        for (int q = tid; q < 128 * 16; q += 256) {
            int row = q >> 4;
            int c = (q & 15) << 2;
            uint4 v = *(const uint4*)(Wb + (size_t)row * 64 + c);
            *(uint4*)(Bu + (size_t)row * 68 + c) = v;
        }
    }
    __syncthreads();

    int lane = tid & 63;
    int wv = tid >> 6;
    int quad = lane >> 4;
    int l15 = lane & 15;
    int r0 = blockIdx.x * 64 + wv * 16;
    int mload = r0 + l15;
    if (mload > M - 1) mload = M - 1;
    const unsigned* Ar = Ab + (size_t)mload * 64 + quad * 4;

    float4v acc[8];
#pragma unroll
    for (int t = 0; t < 8; t++) acc[t] = (float4v){0.f, 0.f, 0.f, 0.f};

    for (int kp = 0; kp < 4; ++kp) {
        uint4 a4 = *(const uint4*)(Ar + kp * 16);
        short8 av;
        av[0] = (short)(a4.x & 0xffff); av[1] = (short)(a4.x >> 16);
        av[2] = (short)(a4.y & 0xffff); av[3] = (short)(a4.y >> 16);
        av[4] = (short)(a4.z & 0xffff); av[5] = (short)(a4.z >> 16);
        av[6] = (short)(a4.w & 0xffff); av[7] = (short)(a4.w >> 16);
        int kb = kp * 32 + quad * 8;
#pragma unroll
        for (int nt = 0; nt < 8; nt++) {
            short8 b8 = *(const short8*)(&Bl[(size_t)(nt * 16 + l15) * 136 + kb]);
            acc[nt] = __builtin_amdgcn_mfma_f32_16x16x32_bf16(av, b8, acc[nt], 0, 0, 0);
        }
    }

    ushort* Cu = (ushort*)Cb;
#pragma unroll
    for (int r = 0; r < 4; r++) {
        int row = r0 + quad * 4 + r;
        if (row < M) {
#pragma unroll
            for (int nt = 0; nt < 8; nt++) {
                Cu[(size_t)row * 128 + nt * 16 + l15] =
                    (ushort)bf16_rne(acc[nt][r]);
            }
        }
    }
}

// ---------------------------------------------------------------------------
// Aggregation core v5c: proven v5 2-deep rotating pipeline, with per-edge
// 15-bit scale unpacked from the record and applied via f32 FMA (VALU has
// headroom — proven supply-bound). Self row scaled by f32 dinv[node].
// Returns sum of q_s*h[s] + dinv[node]*h[node]; caller multiplies by dinv.
// ---------------------------------------------------------------------------
__device__ __forceinline__ float4 agg_core(const uint2* __restrict__ Hu2,
                                           const int* __restrict__ el,
                                           int start, int cnt, int node,
                                           float dvn, int li, int half) {
    float2v a01 = {0.f, 0.f};
    float2v a23 = {0.f, 0.f};
    int groups = ((cnt + 7) & ~7) >> 3;
    if (groups > 0) {
        const int* p = el + start + half * 4;

#define EDGE(cu, rr) {                                                       \
        float qf = (float)((unsigned)(rr) >> 17) * (1.f / 32767.f);          \
        float2v f0, f1;                                                      \
        f0.x = __uint_as_float((cu).x << 16);                                \
        f0.y = __uint_as_float((cu).x & 0xffff0000u);                        \
        f1.x = __uint_as_float((cu).y << 16);                                \
        f1.y = __uint_as_float((cu).y & 0xffff0000u);                        \
        a01.x = fmaf(f0.x, qf, a01.x); a01.y = fmaf(f0.y, qf, a01.y);        \
        a23.x = fmaf(f1.x, qf, a23.x); a23.y = fmaf(f1.y, qf, a23.y);        \
}
        int4 rc = *(const int4*)p;
        uint2 c0 = Hu2[(size_t)(rc.x & 0x1FFFF) * 32 + li];
        uint2 c1 = Hu2[(size_t)(rc.y & 0x1FFFF) * 32 + li];
        uint2 c2 = Hu2[(size_t)(rc.z & 0x1FFFF) * 32 + li];
        uint2 c3 = Hu2[(size_t)(rc.w & 0x1FFFF) * 32 + li];
        int4 rn = *(const int4*)(p + 8);
        for (int g = 0; g < groups; ++g) {
            // in-flight: features for group g+1
            uint2 n0 = Hu2[(size_t)(rn.x & 0x1FFFF) * 32 + li];
            uint2 n1 = Hu2[(size_t)(rn.y & 0x1FFFF) * 32 + li];
            uint2 n2 = Hu2[(size_t)(rn.z & 0x1FFFF) * 32 + li];
            uint2 n3 = Hu2[(size_t)(rn.w & 0x1FFFF) * 32 + li];
            // recs for group g+2
            int4 r2 = *(const int4*)(p + 8 * (g + 2));
            // accumulate group g (per-edge scale from carried rc)
            EDGE(c0, rc.x) EDGE(c1, rc.y) EDGE(c2, rc.z) EDGE(c3, rc.w)
            c0 = n0; c1 = n1; c2 = n2; c3 = n3;
            rc = rn; rn = r2;
        }
#undef EDGE
    }
    float4 acc = make_float4(a01.x, a01.y, a23.x, a23.y);
    acc.x += __shfl_xor(acc.x, 32);
    acc.y += __shfl_xor(acc.y, 32);
    acc.z += __shfl_xor(acc.z, 32);
    acc.w += __shfl_xor(acc.w, 32);
    uint2 sv = Hu2[(size_t)node * 32 + li];  // self row (unscaled)
    float2 s0 = unpack_bf2(sv.x);
    float2 s1 = unpack_bf2(sv.y);
    acc.x = fmaf(s0.x, dvn, acc.x); acc.y = fmaf(s0.y, dvn, acc.y);
    acc.z = fmaf(s1.x, dvn, acc.z); acc.w = fmaf(s1.y, dvn, acc.w);
    return acc;
}

// Layer 1: *dinv, + b1, BN(eval), ReLU -> H1 packed bf16
__global__ __launch_bounds__(256) void agg1_k(
    const unsigned* __restrict__ H, const int* __restrict__ el,
    const int* __restrict__ offsets, const int* __restrict__ counts,
    const float* __restrict__ dinv, const float* __restrict__ b1,
    const float* __restrict__ gamma, const float* __restrict__ beta,
    const float* __restrict__ mean, const float* __restrict__ var,
    unsigned* __restrict__ H1b, int n) {
    int lane = threadIdx.x & 63;
    int li = lane & 31;
    int half = lane >> 5;
    int node = blockIdx.x * 4 + (threadIdx.x >> 6);
    if (node >= n) return;
    float dv = dinv[node];
    float4 acc = agg_core((const uint2*)H, el, offsets[node],
                          counts[(size_t)node * 16], node, dv, li, half);
    if (half == 0) {
        int f0 = li * 4;
        float4 bb = *(const float4*)(b1 + f0);
        float4 mm = *(const float4*)(mean + f0);
        float4 vv = *(const float4*)(var + f0);
        float4 gg = *(const float4*)(gamma + f0);
        float4 be = *(const float4*)(beta + f0);
        float4 o;
        o.x = fmaxf((acc.x * dv + bb.x - mm.x) * rsqrtf(vv.x + BN_EPS) * gg.x + be.x, 0.f);
        o.y = fmaxf((acc.y * dv + bb.y - mm.y) * rsqrtf(vv.y + BN_EPS) * gg.y + be.y, 0.f);
        o.z = fmaxf((acc.z * dv + bb.z - mm.z) * rsqrtf(vv.z + BN_EPS) * gg.z + be.z, 0.f);
        o.w = fmaxf((acc.w * dv + bb.w - mm.w) * rsqrtf(vv.w + BN_EPS) * gg.w + be.w, 0.f);
        uint2 pk;
        pk.x = pack_bf2(o.x, o.y);
        pk.y = pack_bf2(o.z, o.w);
        *(uint2*)(H1b + (size_t)node * 64 + li * 2) = pk;
    }
}

// Layer 2: *dinv, + b2, then JK max with H1 (in-place bf16 H1 -> JK)
__global__ __launch_bounds__(256) void agg2_k(
    const unsigned* __restrict__ H, const int* __restrict__ el,
    const int* __restrict__ offsets, const int* __restrict__ counts,
    const float* __restrict__ dinv, const float* __restrict__ b2,
    unsigned* __restrict__ H1b, int n) {
    int lane = threadIdx.x & 63;
    int li = lane & 31;
    int half = lane >> 5;
    int node = blockIdx.x * 4 + (threadIdx.x >> 6);
    if (node >= n) return;
    float dv = dinv[node];
    float4 acc = agg_core((const uint2*)H, el, offsets[node],
                          counts[(size_t)node * 16], node, dv, li, half);
    if (half == 0) {
        int f0 = li * 4;
        float4 bb = *(const float4*)(b2 + f0);
        uint2* p = (uint2*)(H1b + (size_t)node * 64 + li * 2);
        uint2 hv = *p;
        float2 ha = unpack_bf2(hv.x);
        float2 hb = unpack_bf2(hv.y);
        float4 o;
        o.x = fmaxf(ha.x, acc.x * dv + bb.x);
        o.y = fmaxf(ha.y, acc.y * dv + bb.y);
        o.z = fmaxf(hb.x, acc.z * dv + bb.z);
        o.w = fmaxf(hb.y, acc.w * dv + bb.w);
        uint2 pk;
        pk.x = pack_bf2(o.x, o.y);
        pk.y = pack_bf2(o.z, o.w);
        *p = pk;
    }
}

// ---------------------------------------------------------------------------
// Head: tiled GEMM (64 nodes x 48 cols, K=128) + fused log_softmax.
// JK input is packed bf16 [n][64 uints].
// ---------------------------------------------------------------------------
__global__ __launch_bounds__(256) void head_k(const unsigned* __restrict__ JKb,
                                              const float* __restrict__ Wf,
                                              const float* __restrict__ bf,
                                              float* __restrict__ out, int n) {
    __shared__ __align__(16) float Bs[48 * 132];  // [col][k], stride 132
    __shared__ __align__(16) float As[64 * 36];   // [row][k-in-panel], stride 36
    int tid = threadIdx.x;
    for (int p = tid; p < 47 * 32; p += 256) {
        int c = p >> 5;          // 0..46
        int k0 = (p & 31) << 2;  // 0,4,...,124
        float4 v;
        v.x = Wf[(size_t)(k0 + 0) * DOUT + c];
        v.y = Wf[(size_t)(k0 + 1) * DOUT + c];
        v.z = Wf[(size_t)(k0 + 2) * DOUT + c];
        v.w = Wf[(size_t)(k0 + 3) * DOUT + c];
        *(float4*)(&Bs[c * 132 + k0]) = v;
    }
    int tx = tid & 15;   // col group: cols [3*tx, 3*tx+3)
    int ty = tid >> 4;   // row group: rows [4*ty, 4*ty+4)
    int node0 = blockIdx.x * 64;

    float acc[4][3];
#pragma unroll
    for (int i = 0; i < 4; i++)
#pragma unroll
        for (int j = 0; j < 3; j++) acc[i][j] = 0.f;

    for (int kk = 0; kk < 128; kk += 32) {
        __syncthreads();
        for (int l = tid; l < 512; l += 256) {
            int r = l >> 3;
            int c4 = (l & 7) << 2;
            int row = node0 + r;
            float4 v = make_float4(0.f, 0.f, 0.f, 0.f);
            if (row < n) {
                uint2 u = *(const uint2*)(JKb + (size_t)row * 64 + ((kk + c4) >> 1));
                float2 f0 = unpack_bf2(u.x);
                float2 f1 = unpack_bf2(u.y);
                v = make_float4(f0.x, f0.y, f1.x, f1.y);
            }
            *(float4*)(&As[r * 36 + c4]) = v;
        }
        __syncthreads();
#pragma unroll
        for (int k4 = 0; k4 < 32; k4 += 4) {
            float4 a0 = *(const float4*)(&As[(ty * 4 + 0) * 36 + k4]);
            float4 a1 = *(const float4*)(&As[(ty * 4 + 1) * 36 + k4]);
            float4 a2 = *(const float4*)(&As[(ty * 4 + 2) * 36 + k4]);
            float4 a3 = *(const float4*)(&As[(ty * 4 + 3) * 36 + k4]);
            float4 b0 = *(const float4*)(&Bs[(tx * 3 + 0) * 132 + kk + k4]);
            float4 b1 = *(const float4*)(&Bs[(tx * 3 + 1) * 132 + kk + k4]);
            float4 b2 = *(const float4*)(&Bs[(tx * 3 + 2) * 132 + kk + k4]);
#define DOT_ROW(i, a)                                                        \
            acc[i][0] = fmaf(a.x, b0.x, acc[i][0]);                          \
            acc[i][0] = fmaf(a.y, b0.y, acc[i][0]);                          \
            acc[i][0] = fmaf(a.z, b0.z, acc[i][0]);                          \
            acc[i][0] = fmaf(a.w, b0.w, acc[i][0]);                          \
            acc[i][1] = fmaf(a.x, b1.x, acc[i][1]);                          \
            acc[i][1] = fmaf(a.y, b1.y, acc[i][1]);                          \
            acc[i][1] = fmaf(a.z, b1.z, acc[i][1]);                          \
            acc[i][1] = fmaf(a.w, b1.w, acc[i][1]);                          \
            acc[i][2] = fmaf(a.x, b2.x, acc[i][2]);                          \
            acc[i][2] = fmaf(a.y, b2.y, acc[i][2]);                          \
            acc[i][2] = fmaf(a.z, b2.z, acc[i][2]);                          \
            acc[i][2] = fmaf(a.w, b2.w, acc[i][2]);
            DOT_ROW(0, a0)
            DOT_ROW(1, a1)
            DOT_ROW(2, a2)
            DOT_ROW(3, a3)
#undef DOT_ROW
        }
    }

    float bfv[3];
#pragma unroll
    for (int j = 0; j < 3; j++) {
        int c = tx * 3 + j;
        bfv[j] = (c < DOUT) ? bf[c] : 0.f;
    }
#pragma unroll
    for (int i = 0; i < 4; i++) {
        int node = node0 + ty * 4 + i;
        float l0 = acc[i][0] + bfv[0];
        float l1 = acc[i][1] + bfv[1];
        float l2 = acc[i][2] + bfv[2];
        bool v2ok = (tx * 3 + 2) < DOUT;  // only col 47 (tx=15,j=2) invalid
        float m = fmaxf(l0, l1);
        if (v2ok) m = fmaxf(m, l2);
        for (int off = 8; off >= 1; off >>= 1) m = fmaxf(m, __shfl_xor(m, off));
        float s = expf(l0 - m) + expf(l1 - m) + (v2ok ? expf(l2 - m) : 0.f);
        for (int off = 8; off >= 1; off >>= 1) s += __shfl_xor(s, off);
        float ls = m + logf(s);
        if (node < n) {
            float* o = out + (size_t)node * DOUT + tx * 3;
            o[0] = l0 - ls;
            o[1] = l1 - ls;
            if (v2ok) o[2] = l2 - ls;
        }
    }
}

// ---------------------------------------------------------------------------
extern "C" void kernel_launch(void* const* d_in, const int* in_sizes, int n_in,
                              void* d_out, int out_size, void* d_ws, size_t ws_size,
                              hipStream_t stream) {
    const float* x     = (const float*)d_in[0];
    const int*   ei    = (const int*)d_in[1];
    const float* W1    = (const float*)d_in[2];
    const float* b1    = (const float*)d_in[3];
    const float* gamma = (const float*)d_in[4];
    const float* beta  = (const float*)d_in[5];
    const float* mean  = (const float*)d_in[6];
    const float* var   = (const float*)d_in[7];
    const float* W2    = (const float*)d_in[8];
    const float* b2    = (const float*)d_in[9];
    const float* Wf    = (const float*)d_in[10];
    const float* bf    = (const float*)d_in[11];
    float* out = (float*)d_out;

    int N_ = in_sizes[0] / 128;
    int E_ = in_sizes[1] / 2;
    const int* src = ei;
    const int* dst = ei + E_;

    char* ws = (char*)d_ws;
    unsigned* bufA = (unsigned*)ws; ws += (size_t)(N_ + 1) * 64 * 4;  // bf16 table + sentinel row
    unsigned* h1b  = (unsigned*)ws; ws += (size_t)N_ * 64 * 4;        // bf16 h1 / JK
    int* countsP   = (int*)ws;    ws += (size_t)N_ * 16 * 4;          // padded: 1 counter / 64 B
    int*   offsets = (int*)ws;    ws += (size_t)N_ * 4;
    float* dinv    = (float*)ws;  ws += (size_t)N_ * 4;
    int*   rank    = (int*)ws;    ws += (size_t)E_ * 4;
    // padded edge list (src|q15<<17 records): sum((c+7)&~7) <= E+7N; +128 tail
    int*   el      = (int*)ws;    ws += ((size_t)E_ + 7 * (size_t)N_ + 128) * 4;
    int*   bsums   = (int*)ws;    ws += 1024 * 4;
    unsigned* W1b  = (unsigned*)ws; ws += 128 * 64 * 4;               // bf16 W^T [n][k]
    unsigned* W2b  = (unsigned*)ws; ws += 128 * 64 * 4;

    int nb = (N_ + 1023) / 1024;
    int gemmBlocks = (N_ + 63) / 64;
    int countBlocks = (E_ + 2047) / 2048;               // 8 edges/thread
    int pairs = countBlocks > (gemmBlocks + 1) / 2 ? countBlocks : (gemmBlocks + 1) / 2;
    int fusedGrid = 3 * pairs;
    int edgeBlocks = (E_ + 1023) / 1024;                // 4 edges/thread (scatter)
    int zeroBlocks = (N_ * 4 + 255) / 256;              // int4 stores over N*16 ints

    prep_k<<<2 + zeroBlocks, 256, 0, stream>>>(W1, W2, W1b, W2b, countsP, bufA, N_);
    fused_gc_k<<<fusedGrid, 256, 0, stream>>>(x, W1b, bufA, N_,
                                              dst, countsP, rank, E_, gemmBlocks);
    scan1_k<<<nb, 256, 0, stream>>>(countsP, offsets, bsums, N_);
    scan2_k<<<1, 128, 0, stream>>>(bsums, nb, el, N_);
    finalize_k<<<(N_ + 255) / 256, 256, 0, stream>>>(offsets, dinv,
                                                     countsP, bsums, el, N_);
    scatter_k<<<edgeBlocks, 256, 0, stream>>>(src, dst, rank, offsets, dinv, el, E_);

    // layer 1 aggregation (per-edge q15 scale)
    agg1_k<<<(N_ + 3) / 4, 256, 0, stream>>>(bufA, el, offsets, countsP, dinv,
                                             b1, gamma, beta, mean, var, h1b, N_);
    // layer 2 (bf16 A -> single-mfma gemm, unscaled table)
    gemm_bf16_k<<<gemmBlocks, 256, 0, stream>>>(h1b, W2b, bufA, N_);
    agg2_k<<<(N_ + 3) / 4, 256, 0, stream>>>(bufA, el, offsets, countsP, dinv,
                                             b2, h1b, N_);
    // head: h1b now holds jk = max(h1, h2) in bf16; 64 nodes per block
    head_k<<<(N_ + 63) / 64, 256, 0, stream>>>(h1b, Wf, bf, out, N_);
}